// Round 8
// baseline (3094.437 us; speedup 1.0000x reference)
//
#include <hip/hip_runtime.h>
#include <hip/hip_bf16.h>
#include <cstdint>

// VQ quantizer: dist argmin over 8192 codes, gather, loss.
// R8: R7's 3-phase counted schedule, but 2-buffer LDS (64KB static) => 2
// blocks/CU (4 waves/SIMD): cross-block overlap fills the MFMA-idle during
// read/barrier segments. All 4 stage loads issue in phase 1 so the step-end
// vmcnt(0) waits on ~1000-cycle-old loads (no stall). Math core unchanged.

typedef __bf16 bf16x8 __attribute__((ext_vector_type(8)));
typedef __bf16 bf16x4 __attribute__((ext_vector_type(4)));
typedef float  f32x16 __attribute__((ext_vector_type(16)));

#define N_ROWS  16384
#define N_CODES 8192
#define DDIM    256
#define NT      16             // 256 / BK16
#define BUFB    32768          // xh 8K | xl 8K | eh 8K | el 8K

#define STAGE16(gptr, lptr) __builtin_amdgcn_global_load_lds( \
    (const __attribute__((address_space(1))) void*)(gptr),    \
    (__attribute__((address_space(3))) void*)(lptr), 16, 0, 0)

#define SBAR() do { asm volatile("" ::: "memory"); \
                    __builtin_amdgcn_s_barrier();  \
                    asm volatile("" ::: "memory"); } while (0)
#define WAITVM(N) asm volatile("s_waitcnt vmcnt(" #N ")" ::: "memory")
#define LGKM0() do { asm volatile("s_waitcnt lgkmcnt(0)" ::: "memory"); \
                     __builtin_amdgcn_sched_barrier(0); } while (0)

// ---------- prep: split x (f32) into bf16 hi/lo planes ----------
__global__ void prep_x_k(const float* __restrict__ x,
                         __bf16* __restrict__ xhi, __bf16* __restrict__ xlo) {
  int i = blockIdx.x * 256 + threadIdx.x;
  float4 v = reinterpret_cast<const float4*>(x)[i];
  float a[4] = {v.x, v.y, v.z, v.w};
  bf16x4 h, l;
#pragma unroll
  for (int j = 0; j < 4; ++j) {
    __bf16 hh = (__bf16)a[j];
    h[j] = hh;
    l[j] = (__bf16)(a[j] - (float)hh);
  }
  reinterpret_cast<bf16x4*>(xhi)[i] = h;
  reinterpret_cast<bf16x4*>(xlo)[i] = l;
}

// ---------- prep: transpose emb [256][8192] -> [8192][256]; split + f32 copy ----------
__global__ void prep_e_k(const float* __restrict__ emb,
                         __bf16* __restrict__ ehi, __bf16* __restrict__ elo,
                         float* __restrict__ embT) {
  __shared__ float tile[64][65];
  const int kb = blockIdx.x * 64, db = blockIdx.y * 64;
  const int t = threadIdx.x;
  const int tk = t & 63, td = t >> 6;
#pragma unroll
  for (int c = 0; c < 16; ++c) {
    int d = c * 4 + td;
    tile[d][tk] = emb[(size_t)(db + d) * N_CODES + kb + tk];
  }
  __syncthreads();
#pragma unroll
  for (int c = 0; c < 16; ++c) {
    int k = c * 4 + td;
    int d = tk;
    float v = tile[d][k];
    size_t o = (size_t)(kb + k) * DDIM + db + d;
    __bf16 h = (__bf16)v;
    embT[o] = v;
    ehi[o] = h;
    elo[o] = (__bf16)(v - (float)h);
  }
}

// ---------- prep: ||e_k||^2 in exact f32 ----------
__global__ void enorm_k(const float* __restrict__ emb, float* __restrict__ enorm) {
  int k = blockIdx.x * 256 + threadIdx.x;
  float s = 0.f;
  for (int d = 0; d < DDIM; ++d) {
    float v = emb[(size_t)d * N_CODES + k];
    s += v * v;
  }
  enorm[k] = s;
}

// ---------- main: 256x256 tile, 8 waves, BK=16, 2-buf / 2-blocks-per-CU ----
// LDS buffer (32KB), 1KB units (64 lanes x 16B, one frag each):
//   [0,8): xh row-unit | [8,16): xl | [16,24): eh code-unit | [24,32): el
// Wave w stages units {xh[w], eh[w], xl[w], el[w]} (1KB each) per step,
// all issued in phase 1 (step-end vmcnt(0) then waits on old loads only).
// A-operand = e-frag (code=lane&31, k-chunk=lane>>5), B-operand = x-frag.
// C layout (m74): col(lane&31)=xrow, code=(reg&3)+8*(reg>>2)+4*(lane>>5).
__global__ __launch_bounds__(512, 4) void vq_main_k(
    const __bf16* __restrict__ xhi, const __bf16* __restrict__ xlo,
    const __bf16* __restrict__ ehi, const __bf16* __restrict__ elo,
    const float* __restrict__ enorm, unsigned long long* __restrict__ keys) {
  __shared__ alignas(16) unsigned char smem[2][BUFB];     // 64KB -> 2 blocks/CU

  const int tid = threadIdx.x;
  const int wid = tid >> 6, lane = tid & 63;
  const int cg = wid >> 2, rg = wid & 3;      // code-half, row-quarter
  const int l31 = lane & 31, lh = lane >> 5;

  // XCD swizzle: each XCD owns an 8-bm window (2048 rows, L2-resident)
  // swept over all 32 bn panels. 2048 % 8 == 0 -> bijective.
  const int orig = blockIdx.x;
  const int j = orig >> 3;
  const int bm = (orig & 7) * 8 + (j & 7);    // 0..63
  const int bn = j >> 3;                      // 0..31

  // acc init = -||e||^2/2  (argmin dist == argmax(dot - en/2))
  const int cbase = bn * 256 + cg * 128 + lh * 4;
  f32x16 acc[4][2];
#pragma unroll
  for (int c = 0; c < 4; ++c) {
    f32x16 ci;
#pragma unroll
    for (int q = 0; q < 4; ++q)
#pragma unroll
      for (int r = 0; r < 4; ++r)
        ci[q * 4 + r] = -0.5f * enorm[cbase + c * 32 + q * 8 + r];
    acc[c][0] = ci; acc[c][1] = ci;
  }
  __builtin_amdgcn_sched_barrier(0);   // enorm waits resolve before staging

  // staging sources (wave-owned row/code unit = wid)
  const size_t aoff = (size_t)(bm * 256 + wid * 32 + l31) * 512 + (size_t)lh * 16;
  const size_t boff = (size_t)(bn * 256 + wid * 32 + l31) * 512 + (size_t)lh * 16;
  const char* pxh = (const char*)xhi + aoff;
  const char* pxl = (const char*)xlo + aoff;
  const char* peh = (const char*)ehi + boff;
  const char* pel = (const char*)elo + boff;
  const int dxh = wid * 1024, dxl = 8192 + wid * 1024;
  const int deh = 16384 + wid * 1024, del = 24576 + wid * 1024;

  // fragment read offsets (lane-linear)
  const int xrd = rg * 2048 + lane * 16;           // + r*1024 ; xl at +8192
  const int erd = 16384 + cg * 4096 + lane * 16;   // + c*1024 ; el at +8192

  // prologue: step 0 -> buf0
  STAGE16(pxh, smem[0] + dxh); STAGE16(peh, smem[0] + deh);
  STAGE16(pxl, smem[0] + dxl); STAGE16(pel, smem[0] + del);
  WAITVM(0);
  SBAR();

  int cur = 0;
#pragma unroll 1
  for (int t = 0; t < NT; ++t) {
    const unsigned char* rb = smem[cur];
    unsigned char* wb = smem[cur ^ 1];
    const size_t kb = (size_t)(t + 1) * 32;

    // ---- phase 1: read eh(4)+xh(2); stage ALL 4 units of t+1; 8 MFMA hh ----
    bf16x8 ehf[4], xhf[2];
#pragma unroll
    for (int c = 0; c < 4; ++c) ehf[c] = *(const bf16x8*)(rb + erd + c * 1024);
#pragma unroll
    for (int r = 0; r < 2; ++r) xhf[r] = *(const bf16x8*)(rb + xrd + r * 1024);
    if (t < NT - 1) {
      STAGE16(pxh + kb, wb + dxh);
      STAGE16(peh + kb, wb + deh);
      STAGE16(pxl + kb, wb + dxl);
      STAGE16(pel + kb, wb + del);
    }
    SBAR();
    LGKM0();
    __builtin_amdgcn_s_setprio(1);
#pragma unroll
    for (int c = 0; c < 4; ++c)
#pragma unroll
      for (int r = 0; r < 2; ++r)
        acc[c][r] = __builtin_amdgcn_mfma_f32_32x32x16_bf16(ehf[c], xhf[r], acc[c][r], 0, 0, 0);
    __builtin_amdgcn_s_setprio(0);
    SBAR();

    // ---- phase 2: read xl(2), 8 MFMA hl ----
    bf16x8 xlf[2];
#pragma unroll
    for (int r = 0; r < 2; ++r) xlf[r] = *(const bf16x8*)(rb + 8192 + xrd + r * 1024);
    SBAR();
    LGKM0();
    __builtin_amdgcn_s_setprio(1);
#pragma unroll
    for (int c = 0; c < 4; ++c)
#pragma unroll
      for (int r = 0; r < 2; ++r)
        acc[c][r] = __builtin_amdgcn_mfma_f32_32x32x16_bf16(ehf[c], xlf[r], acc[c][r], 0, 0, 0);
    __builtin_amdgcn_s_setprio(0);
    SBAR();

    // ---- phase 3: read el(4), 8 MFMA lh; drain old stages; swap ----
    bf16x8 elf[4];
#pragma unroll
    for (int c = 0; c < 4; ++c) elf[c] = *(const bf16x8*)(rb + 8192 + erd + c * 1024);
    SBAR();
    LGKM0();
    __builtin_amdgcn_s_setprio(1);
#pragma unroll
    for (int c = 0; c < 4; ++c)
#pragma unroll
      for (int r = 0; r < 2; ++r)
        acc[c][r] = __builtin_amdgcn_mfma_f32_32x32x16_bf16(elf[c], xhf[r], acc[c][r], 0, 0, 0);
    __builtin_amdgcn_s_setprio(0);
    WAITVM(0);       // stages were issued in phase 1 (~3 phases ago): no stall
    SBAR();
    cur ^= 1;
  }

  // epilogue: per lane, xrow = bm*256 + rg*64 + r*32 + l31 holds 128 scores
  // (4 code-frags x 32). Ascending-code scan, strict > -> smallest code on tie.
#pragma unroll
  for (int r = 0; r < 2; ++r) {
    float bv = -3.4e38f;
    unsigned bcode = 0;
#pragma unroll
    for (int c = 0; c < 4; ++c)
#pragma unroll
      for (int q = 0; q < 4; ++q)
#pragma unroll
        for (int rr = 0; rr < 4; ++rr) {
          float v = acc[c][r][q * 4 + rr];
          unsigned cd = (unsigned)(cbase + c * 32 + q * 8 + rr);
          if (v > bv) { bv = v; bcode = cd; }
        }
    unsigned u = __float_as_uint(bv);
    u = (u & 0x80000000u) ? ~u : (u | 0x80000000u);        // order-preserving
    unsigned long long key =
        ((unsigned long long)u << 32) | (unsigned)(0xFFFFFFFFu ^ bcode);
    unsigned olo = __shfl_xor((unsigned)key, 32, 64);
    unsigned ohi = __shfl_xor((unsigned)(key >> 32), 32, 64);
    unsigned long long okey = ((unsigned long long)ohi << 32) | olo;
    if (okey > key) key = okey;
    if (lane < 32)
      atomicMax(&keys[bm * 256 + rg * 64 + r * 32 + l31], key);
  }
}

// ---------- gather q (exact f32), q_st out, per-row squared error ----------
__global__ void gather_k(const float* __restrict__ x, const float* __restrict__ embT,
                         const unsigned long long* __restrict__ keys,
                         float* __restrict__ qout, float* __restrict__ rowsum) {
  const int row = blockIdx.x;
  const int lane = threadIdx.x;
  const unsigned low = (unsigned)(keys[row] & 0xffffffffull);
  const int idx = (int)(~low);                 // stored 0xFFFFFFFF ^ code
  float4 q  = reinterpret_cast<const float4*>(embT + (size_t)idx * DDIM)[lane];
  float4 xv = reinterpret_cast<const float4*>(x + (size_t)row * DDIM)[lane];
  reinterpret_cast<float4*>(qout + (size_t)row * DDIM)[lane] = q;
  float dx = q.x - xv.x, dy = q.y - xv.y, dz = q.z - xv.z, dw = q.w - xv.w;
  float s = dx * dx + dy * dy + dz * dz + dw * dw;
#pragma unroll
  for (int mk = 32; mk; mk >>= 1) s += __shfl_xor(s, mk, 64);
  if (lane == 0) rowsum[row] = s;
}

// ---------- deterministic final loss reduce ----------
__global__ void loss_k(const float* __restrict__ rowsum, float* __restrict__ out) {
  __shared__ float sm[4];
  const int t = threadIdx.x;
  float s = 0.f;
  for (int j = t; j < N_ROWS; j += 256) s += rowsum[j];
#pragma unroll
  for (int mk = 32; mk; mk >>= 1) s += __shfl_xor(s, mk, 64);
  if ((t & 63) == 0) sm[t >> 6] = s;
  __syncthreads();
  if (t == 0) out[0] = 2.0f * (sm[0] + sm[1] + sm[2] + sm[3]) / (float)(N_ROWS * DDIM);
}

extern "C" void kernel_launch(void* const* d_in, const int* in_sizes, int n_in,
                              void* d_out, int out_size, void* d_ws, size_t ws_size,
                              hipStream_t stream) {
  const float* x   = (const float*)d_in[0];          // [16,1024,256] f32
  const float* emb = (const float*)d_in[1];          // [256,8192] f32
  float* qout = (float*)d_out;                       // 4,194,304 q_st + 1 loss

  char* w = (char*)d_ws;
  unsigned long long* keys = (unsigned long long*)w;                 // 128 KB
  float* rowsum = (float*)(w + 131072);                              // 64 KB
  __bf16* xhi = (__bf16*)(w + 196608);                               // 8 MB
  __bf16* xlo = xhi + (size_t)N_ROWS * DDIM;                         // 8 MB
  __bf16* ehi = xlo + (size_t)N_ROWS * DDIM;                         // 4 MB
  __bf16* elo = ehi + (size_t)N_CODES * DDIM;                        // 4 MB
  float*  embT = (float*)(elo + (size_t)N_CODES * DDIM);             // 8 MB
  float*  enorm = embT + (size_t)N_CODES * DDIM;                     // 32 KB

  hipMemsetAsync(keys, 0, N_ROWS * sizeof(unsigned long long), stream);  // atomicMax
  prep_x_k<<<4096, 256, 0, stream>>>(x, xhi, xlo);
  prep_e_k<<<dim3(N_CODES / 64, DDIM / 64), 256, 0, stream>>>(emb, ehi, elo, embT);
  enorm_k<<<N_CODES / 256, 256, 0, stream>>>(emb, enorm);
  vq_main_k<<<2048, 512, 0, stream>>>(xhi, xlo, ehi, elo, enorm, keys);
  gather_k<<<N_ROWS, 64, 0, stream>>>(x, embT, keys, qout, rowsum);
  loss_k<<<1, 256, 0, stream>>>(rowsum, qout + (size_t)N_ROWS * DDIM);
}

// Round 9
// 271.803 us; speedup vs baseline: 11.3849x; 11.3849x over previous
//
#include <hip/hip_runtime.h>
#include <hip/hip_bf16.h>
#include <cstdint>

// VQ quantizer: dist argmin over 8192 codes, gather, loss.
// R9: R7's 3-phase counted schedule and math core, reorganized into 4-wave
// 256-thread blocks (tile 128 rows x 256 codes, 2x24KB LDS) so TWO blocks
// (independent barrier groups) co-reside per CU: one block's MFMA fills the
// other's read/barrier gaps. launch_bounds(256,2) caps regs at 256 (no R8
// spill). Stage loads issue in phase 1; step-end vmcnt(0) sees old loads.

typedef __bf16 bf16x8 __attribute__((ext_vector_type(8)));
typedef __bf16 bf16x4 __attribute__((ext_vector_type(4)));
typedef float  f32x16 __attribute__((ext_vector_type(16)));

#define N_ROWS  16384
#define N_CODES 8192
#define DDIM    256
#define NT      16             // 256 / BK16
#define BUFB    24576          // xh 4K | xl 4K | eh 8K | el 8K

#define STAGE16(gptr, lptr) __builtin_amdgcn_global_load_lds( \
    (const __attribute__((address_space(1))) void*)(gptr),    \
    (__attribute__((address_space(3))) void*)(lptr), 16, 0, 0)

#define SBAR() do { asm volatile("" ::: "memory"); \
                    __builtin_amdgcn_s_barrier();  \
                    asm volatile("" ::: "memory"); } while (0)
#define WAITVM(N) asm volatile("s_waitcnt vmcnt(" #N ")" ::: "memory")
#define LGKM0() do { asm volatile("s_waitcnt lgkmcnt(0)" ::: "memory"); \
                     __builtin_amdgcn_sched_barrier(0); } while (0)

// ---------- prep: split x (f32) into bf16 hi/lo planes ----------
__global__ void prep_x_k(const float* __restrict__ x,
                         __bf16* __restrict__ xhi, __bf16* __restrict__ xlo) {
  int i = blockIdx.x * 256 + threadIdx.x;
  float4 v = reinterpret_cast<const float4*>(x)[i];
  float a[4] = {v.x, v.y, v.z, v.w};
  bf16x4 h, l;
#pragma unroll
  for (int j = 0; j < 4; ++j) {
    __bf16 hh = (__bf16)a[j];
    h[j] = hh;
    l[j] = (__bf16)(a[j] - (float)hh);
  }
  reinterpret_cast<bf16x4*>(xhi)[i] = h;
  reinterpret_cast<bf16x4*>(xlo)[i] = l;
}

// ---------- prep: transpose emb [256][8192] -> [8192][256]; split + f32 copy ----------
__global__ void prep_e_k(const float* __restrict__ emb,
                         __bf16* __restrict__ ehi, __bf16* __restrict__ elo,
                         float* __restrict__ embT) {
  __shared__ float tile[64][65];
  const int kb = blockIdx.x * 64, db = blockIdx.y * 64;
  const int t = threadIdx.x;
  const int tk = t & 63, td = t >> 6;
#pragma unroll
  for (int c = 0; c < 16; ++c) {
    int d = c * 4 + td;
    tile[d][tk] = emb[(size_t)(db + d) * N_CODES + kb + tk];
  }
  __syncthreads();
#pragma unroll
  for (int c = 0; c < 16; ++c) {
    int k = c * 4 + td;
    int d = tk;
    float v = tile[d][k];
    size_t o = (size_t)(kb + k) * DDIM + db + d;
    __bf16 h = (__bf16)v;
    embT[o] = v;
    ehi[o] = h;
    elo[o] = (__bf16)(v - (float)h);
  }
}

// ---------- prep: ||e_k||^2 in exact f32 ----------
__global__ void enorm_k(const float* __restrict__ emb, float* __restrict__ enorm) {
  int k = blockIdx.x * 256 + threadIdx.x;
  float s = 0.f;
  for (int d = 0; d < DDIM; ++d) {
    float v = emb[(size_t)d * N_CODES + k];
    s += v * v;
  }
  enorm[k] = s;
}

// ---------- main: 128x256 tile, 4 waves (2cg x 2rg), BK=16, 2-buf ----------
// LDS buffer (24KB), 1KB units (64 lanes x 16B, one frag each):
//   [0,4K): xh units 0-3 | [4K,8K): xl | [8K,16K): eh units 0-7 | [16K,24K): el
// Wave w stages {xh[w], xl[w], eh[2w], eh[2w+1], el[2w], el[2w+1]} per step,
// all in phase 1 (step-end vmcnt(0) waits on ~3-phase-old loads only).
// A-operand = e-frag (code=lane&31, k-chunk=lane>>5), B-operand = x-frag.
// C layout (m74): col(lane&31)=xrow, code=(reg&3)+8*(reg>>2)+4*(lane>>5).
__global__ __launch_bounds__(256, 2) void vq_main_k(
    const __bf16* __restrict__ xhi, const __bf16* __restrict__ xlo,
    const __bf16* __restrict__ ehi, const __bf16* __restrict__ elo,
    const float* __restrict__ enorm, unsigned long long* __restrict__ keys) {
  __shared__ alignas(16) unsigned char smem[2][BUFB];     // 48KB static

  const int tid = threadIdx.x;
  const int wid = tid >> 6, lane = tid & 63;
  const int cg = wid >> 1, rg = wid & 1;      // code-half(128), row-half(64)
  const int l31 = lane & 31, lh = lane >> 5;

  // XCD swizzle: each XCD owns a 16-bm window (2048 rows, 2MB hi+lo,
  // L2-resident) swept over all 32 bn panels. 4096 % 8 == 0 -> bijective.
  const int orig = blockIdx.x;
  const int j = orig >> 3;
  const int bm = (orig & 7) * 16 + (j & 15);  // 0..127
  const int bn = j >> 4;                      // 0..31

  // acc init = -||e||^2/2  (argmin dist == argmax(dot - en/2))
  const int cbase = bn * 256 + cg * 128 + lh * 4;
  f32x16 acc[4][2];
#pragma unroll
  for (int c = 0; c < 4; ++c) {
    f32x16 ci;
#pragma unroll
    for (int q = 0; q < 4; ++q)
#pragma unroll
      for (int r = 0; r < 4; ++r)
        ci[q * 4 + r] = -0.5f * enorm[cbase + c * 32 + q * 8 + r];
    acc[c][0] = ci; acc[c][1] = ci;
  }
  __builtin_amdgcn_sched_barrier(0);   // enorm waits resolve before staging

  // staging sources (wave-owned units: x unit wid, e units 2wid, 2wid+1)
  const size_t aoff = (size_t)(bm * 128 + wid * 32 + l31) * 512 + (size_t)lh * 16;
  const size_t boff = (size_t)(bn * 256 + wid * 64 + l31) * 512 + (size_t)lh * 16;
  const char* pxh = (const char*)xhi + aoff;
  const char* pxl = (const char*)xlo + aoff;
  const char* peh = (const char*)ehi + boff;    // +16384 = second unit
  const char* pel = (const char*)elo + boff;
  const int dxh = wid * 1024;
  const int dxl = 4096 + wid * 1024;
  const int deh = 8192 + 2 * wid * 1024;        // 2KB per wave
  const int del = 16384 + 2 * wid * 1024;

  // fragment read offsets (lane-linear)
  const int xrd = rg * 2048 + lane * 16;           // + r*1024 ; xl at +4096
  const int erd = 8192 + cg * 4096 + lane * 16;    // + c*1024 ; el at +8192

  // prologue: step 0 -> buf0
  STAGE16(pxh, smem[0] + dxh);
  STAGE16(pxl, smem[0] + dxl);
  STAGE16(peh, smem[0] + deh);
  STAGE16(peh + 16384, smem[0] + deh + 1024);
  STAGE16(pel, smem[0] + del);
  STAGE16(pel + 16384, smem[0] + del + 1024);
  WAITVM(0);
  SBAR();

  int cur = 0;
#pragma unroll 1
  for (int t = 0; t < NT; ++t) {
    const unsigned char* rb = smem[cur];
    unsigned char* wb = smem[cur ^ 1];
    const size_t kb = (size_t)(t + 1) * 32;

    // ---- phase 1: read eh(4)+xh(2); stage ALL 6 units of t+1; 8 MFMA hh ----
    bf16x8 ehf[4], xhf[2];
#pragma unroll
    for (int c = 0; c < 4; ++c) ehf[c] = *(const bf16x8*)(rb + erd + c * 1024);
#pragma unroll
    for (int r = 0; r < 2; ++r) xhf[r] = *(const bf16x8*)(rb + xrd + r * 1024);
    if (t < NT - 1) {
      STAGE16(pxh + kb, wb + dxh);
      STAGE16(pxl + kb, wb + dxl);
      STAGE16(peh + kb, wb + deh);
      STAGE16(peh + 16384 + kb, wb + deh + 1024);
      STAGE16(pel + kb, wb + del);
      STAGE16(pel + 16384 + kb, wb + del + 1024);
    }
    SBAR();
    LGKM0();
    __builtin_amdgcn_s_setprio(1);
#pragma unroll
    for (int c = 0; c < 4; ++c)
#pragma unroll
      for (int r = 0; r < 2; ++r)
        acc[c][r] = __builtin_amdgcn_mfma_f32_32x32x16_bf16(ehf[c], xhf[r], acc[c][r], 0, 0, 0);
    __builtin_amdgcn_s_setprio(0);
    SBAR();

    // ---- phase 2: read xl(2), 8 MFMA hl ----
    bf16x8 xlf[2];
#pragma unroll
    for (int r = 0; r < 2; ++r) xlf[r] = *(const bf16x8*)(rb + 4096 + xrd + r * 1024);
    SBAR();
    LGKM0();
    __builtin_amdgcn_s_setprio(1);
#pragma unroll
    for (int c = 0; c < 4; ++c)
#pragma unroll
      for (int r = 0; r < 2; ++r)
        acc[c][r] = __builtin_amdgcn_mfma_f32_32x32x16_bf16(ehf[c], xlf[r], acc[c][r], 0, 0, 0);
    __builtin_amdgcn_s_setprio(0);
    SBAR();

    // ---- phase 3: read el(4), 8 MFMA lh; drain old stages; swap ----
    bf16x8 elf[4];
#pragma unroll
    for (int c = 0; c < 4; ++c) elf[c] = *(const bf16x8*)(rb + 8192 + erd + c * 1024);
    SBAR();
    LGKM0();
    __builtin_amdgcn_s_setprio(1);
#pragma unroll
    for (int c = 0; c < 4; ++c)
#pragma unroll
      for (int r = 0; r < 2; ++r)
        acc[c][r] = __builtin_amdgcn_mfma_f32_32x32x16_bf16(elf[c], xhf[r], acc[c][r], 0, 0, 0);
    __builtin_amdgcn_s_setprio(0);
    WAITVM(0);       // stages issued in phase 1 (~3 phases ago): no stall
    SBAR();
    cur ^= 1;
  }

  // epilogue: per lane, xrow = bm*128 + rg*64 + r*32 + l31 holds 128 scores
  // (4 code-frags x 32). Ascending-code scan, strict > -> smallest code on tie.
#pragma unroll
  for (int r = 0; r < 2; ++r) {
    float bv = -3.4e38f;
    unsigned bcode = 0;
#pragma unroll
    for (int c = 0; c < 4; ++c)
#pragma unroll
      for (int q = 0; q < 4; ++q)
#pragma unroll
        for (int rr = 0; rr < 4; ++rr) {
          float v = acc[c][r][q * 4 + rr];
          unsigned cd = (unsigned)(cbase + c * 32 + q * 8 + rr);
          if (v > bv) { bv = v; bcode = cd; }
        }
    unsigned u = __float_as_uint(bv);
    u = (u & 0x80000000u) ? ~u : (u | 0x80000000u);        // order-preserving
    unsigned long long key =
        ((unsigned long long)u << 32) | (unsigned)(0xFFFFFFFFu ^ bcode);
    unsigned olo = __shfl_xor((unsigned)key, 32, 64);
    unsigned ohi = __shfl_xor((unsigned)(key >> 32), 32, 64);
    unsigned long long okey = ((unsigned long long)ohi << 32) | olo;
    if (okey > key) key = okey;
    if (lane < 32)
      atomicMax(&keys[bm * 128 + rg * 64 + r * 32 + l31], key);
  }
}

// ---------- gather q (exact f32), q_st out, per-row squared error ----------
__global__ void gather_k(const float* __restrict__ x, const float* __restrict__ embT,
                         const unsigned long long* __restrict__ keys,
                         float* __restrict__ qout, float* __restrict__ rowsum) {
  const int row = blockIdx.x;
  const int lane = threadIdx.x;
  const unsigned low = (unsigned)(keys[row] & 0xffffffffull);
  const int idx = (int)(~low);                 // stored 0xFFFFFFFF ^ code
  float4 q  = reinterpret_cast<const float4*>(embT + (size_t)idx * DDIM)[lane];
  float4 xv = reinterpret_cast<const float4*>(x + (size_t)row * DDIM)[lane];
  reinterpret_cast<float4*>(qout + (size_t)row * DDIM)[lane] = q;
  float dx = q.x - xv.x, dy = q.y - xv.y, dz = q.z - xv.z, dw = q.w - xv.w;
  float s = dx * dx + dy * dy + dz * dz + dw * dw;
#pragma unroll
  for (int mk = 32; mk; mk >>= 1) s += __shfl_xor(s, mk, 64);
  if (lane == 0) rowsum[row] = s;
}

// ---------- deterministic final loss reduce ----------
__global__ void loss_k(const float* __restrict__ rowsum, float* __restrict__ out) {
  __shared__ float sm[4];
  const int t = threadIdx.x;
  float s = 0.f;
  for (int j = t; j < N_ROWS; j += 256) s += rowsum[j];
#pragma unroll
  for (int mk = 32; mk; mk >>= 1) s += __shfl_xor(s, mk, 64);
  if ((t & 63) == 0) sm[t >> 6] = s;
  __syncthreads();
  if (t == 0) out[0] = 2.0f * (sm[0] + sm[1] + sm[2] + sm[3]) / (float)(N_ROWS * DDIM);
}

extern "C" void kernel_launch(void* const* d_in, const int* in_sizes, int n_in,
                              void* d_out, int out_size, void* d_ws, size_t ws_size,
                              hipStream_t stream) {
  const float* x   = (const float*)d_in[0];          // [16,1024,256] f32
  const float* emb = (const float*)d_in[1];          // [256,8192] f32
  float* qout = (float*)d_out;                       // 4,194,304 q_st + 1 loss

  char* w = (char*)d_ws;
  unsigned long long* keys = (unsigned long long*)w;                 // 128 KB
  float* rowsum = (float*)(w + 131072);                              // 64 KB
  __bf16* xhi = (__bf16*)(w + 196608);                               // 8 MB
  __bf16* xlo = xhi + (size_t)N_ROWS * DDIM;                         // 8 MB
  __bf16* ehi = xlo + (size_t)N_ROWS * DDIM;                         // 4 MB
  __bf16* elo = ehi + (size_t)N_CODES * DDIM;                        // 4 MB
  float*  embT = (float*)(elo + (size_t)N_CODES * DDIM);             // 8 MB
  float*  enorm = embT + (size_t)N_CODES * DDIM;                     // 32 KB

  hipMemsetAsync(keys, 0, N_ROWS * sizeof(unsigned long long), stream);  // atomicMax
  prep_x_k<<<4096, 256, 0, stream>>>(x, xhi, xlo);
  prep_e_k<<<dim3(N_CODES / 64, DDIM / 64), 256, 0, stream>>>(emb, ehi, elo, embT);
  enorm_k<<<N_CODES / 256, 256, 0, stream>>>(emb, enorm);
  vq_main_k<<<4096, 256, 0, stream>>>(xhi, xlo, ehi, elo, enorm, keys);
  gather_k<<<N_ROWS, 64, 0, stream>>>(x, embT, keys, qout, rowsum);
  loss_k<<<1, 256, 0, stream>>>(rowsum, qout + (size_t)N_ROWS * DDIM);
}

// Round 10
// 268.962 us; speedup vs baseline: 11.5051x; 1.0106x over previous
//
#include <hip/hip_runtime.h>
#include <hip/hip_bf16.h>
#include <cstdint>

// VQ quantizer: dist argmin over 8192 codes, gather, loss.
// R10: R7's 3-phase counted schedule with BK=32 steps — 16 MFMA per phase
// (2x R7) amortizes the per-phase read-wait + barrier cost that capped R7 at
// 45.8% MfmaUtil. 2x64KB dynamic LDS (1 block/CU, same occupancy), 8 stage
// loads/wave issued in phase 1, step-end vmcnt(0) sees ~3000-cycle-old loads.

typedef __bf16 bf16x8 __attribute__((ext_vector_type(8)));
typedef __bf16 bf16x4 __attribute__((ext_vector_type(4)));
typedef float  f32x16 __attribute__((ext_vector_type(16)));

#define N_ROWS  16384
#define N_CODES 8192
#define DDIM    256
#define NT      8              // 256 / BK32
#define BUFB    65536          // xh 16K | xl 16K | eh 16K | el 16K

#define STAGE16(gptr, lptr) __builtin_amdgcn_global_load_lds( \
    (const __attribute__((address_space(1))) void*)(gptr),    \
    (__attribute__((address_space(3))) void*)(lptr), 16, 0, 0)

#define SBAR() do { asm volatile("" ::: "memory"); \
                    __builtin_amdgcn_s_barrier();  \
                    asm volatile("" ::: "memory"); } while (0)
#define WAITVM(N) asm volatile("s_waitcnt vmcnt(" #N ")" ::: "memory")
#define LGKM0() do { asm volatile("s_waitcnt lgkmcnt(0)" ::: "memory"); \
                     __builtin_amdgcn_sched_barrier(0); } while (0)

// ---------- prep: split x (f32) into bf16 hi/lo planes ----------
__global__ void prep_x_k(const float* __restrict__ x,
                         __bf16* __restrict__ xhi, __bf16* __restrict__ xlo) {
  int i = blockIdx.x * 256 + threadIdx.x;
  float4 v = reinterpret_cast<const float4*>(x)[i];
  float a[4] = {v.x, v.y, v.z, v.w};
  bf16x4 h, l;
#pragma unroll
  for (int j = 0; j < 4; ++j) {
    __bf16 hh = (__bf16)a[j];
    h[j] = hh;
    l[j] = (__bf16)(a[j] - (float)hh);
  }
  reinterpret_cast<bf16x4*>(xhi)[i] = h;
  reinterpret_cast<bf16x4*>(xlo)[i] = l;
}

// ---------- prep: transpose emb [256][8192] -> [8192][256]; split + f32 copy ----------
__global__ void prep_e_k(const float* __restrict__ emb,
                         __bf16* __restrict__ ehi, __bf16* __restrict__ elo,
                         float* __restrict__ embT) {
  __shared__ float tile[64][65];
  const int kb = blockIdx.x * 64, db = blockIdx.y * 64;
  const int t = threadIdx.x;
  const int tk = t & 63, td = t >> 6;
#pragma unroll
  for (int c = 0; c < 16; ++c) {
    int d = c * 4 + td;
    tile[d][tk] = emb[(size_t)(db + d) * N_CODES + kb + tk];
  }
  __syncthreads();
#pragma unroll
  for (int c = 0; c < 16; ++c) {
    int k = c * 4 + td;
    int d = tk;
    float v = tile[d][k];
    size_t o = (size_t)(kb + k) * DDIM + db + d;
    __bf16 h = (__bf16)v;
    embT[o] = v;
    ehi[o] = h;
    elo[o] = (__bf16)(v - (float)h);
  }
}

// ---------- prep: ||e_k||^2 in exact f32 ----------
__global__ void enorm_k(const float* __restrict__ emb, float* __restrict__ enorm) {
  int k = blockIdx.x * 256 + threadIdx.x;
  float s = 0.f;
  for (int d = 0; d < DDIM; ++d) {
    float v = emb[(size_t)d * N_CODES + k];
    s += v * v;
  }
  enorm[k] = s;
}

// ---------- main: 256x256 tile, 8 waves, BK=32, 3 phases x 16 MFMA ----------
// LDS buffer (64KB), 1KB units (64 lanes x 16B): unit(group g, k-half kh) at
// (g*2+kh)*1024 within each 16KB plane: xh @0 | xl @16K | eh @32K | el @48K.
// Wave w stages its row/code group w: 8 units per step (both kh, 4 planes).
// A-operand = e-frag (code=lane&31, k-chunk=lane>>5), B-operand = x-frag.
// C layout (m74): col(lane&31)=xrow, code=(reg&3)+8*(reg>>2)+4*(lane>>5).
__global__ __launch_bounds__(512, 2) void vq_main_k(
    const __bf16* __restrict__ xhi, const __bf16* __restrict__ xlo,
    const __bf16* __restrict__ ehi, const __bf16* __restrict__ elo,
    const float* __restrict__ enorm, unsigned long long* __restrict__ keys) {
  extern __shared__ __align__(16) unsigned char smem[];   // 2 * 64KB

  const int tid = threadIdx.x;
  const int wid = tid >> 6, lane = tid & 63;
  const int cg = wid >> 2, rg = wid & 3;      // code-half(128), row-quarter(64)
  const int l31 = lane & 31, lh = lane >> 5;

  // XCD swizzle: each XCD owns an 8-bm window (2048 rows, 2MB, L2-resident)
  // swept over all 32 bn panels. 2048 % 8 == 0 -> bijective.
  const int orig = blockIdx.x;
  const int j = orig >> 3;
  const int bm = (orig & 7) * 8 + (j & 7);    // 0..63
  const int bn = j >> 3;                      // 0..31

  // acc init = -||e||^2/2  (argmin dist == argmax(dot - en/2))
  const int cbase = bn * 256 + cg * 128 + lh * 4;
  f32x16 acc[4][2];
#pragma unroll
  for (int c = 0; c < 4; ++c) {
    f32x16 ci;
#pragma unroll
    for (int q = 0; q < 4; ++q)
#pragma unroll
      for (int r = 0; r < 4; ++r)
        ci[q * 4 + r] = -0.5f * enorm[cbase + c * 32 + q * 8 + r];
    acc[c][0] = ci; acc[c][1] = ci;
  }
  __builtin_amdgcn_sched_barrier(0);   // enorm waits resolve before staging

  // staging sources (wave-owned row/code group = wid; 32 rows/codes each)
  const size_t aoff = (size_t)(bm * 256 + wid * 32 + l31) * 512 + (size_t)lh * 16;
  const size_t boff = (size_t)(bn * 256 + wid * 32 + l31) * 512 + (size_t)lh * 16;
  const char* pxh = (const char*)xhi + aoff;
  const char* pxl = (const char*)xlo + aoff;
  const char* peh = (const char*)ehi + boff;
  const char* pel = (const char*)elo + boff;
  const int du0 = wid * 2048;                 // unit pair base (kh=0)

  // fragment read offsets (lane-linear): frag(g,kh) at (g*2+kh)*1024
  const int xrd = rg * 4096 + lane * 16;           // + r*2048 + kh*1024 ; xl +16K
  const int erd = 32768 + cg * 8192 + lane * 16;   // + c*2048 + kh*1024 ; el +16K

  unsigned char* b0 = smem;

  // prologue: step 0 -> buf0 (8 loads per wave)
#pragma unroll
  for (int kh = 0; kh < 2; ++kh) {
    STAGE16(pxh + kh * 32, b0 + du0 + kh * 1024);
    STAGE16(pxl + kh * 32, b0 + 16384 + du0 + kh * 1024);
    STAGE16(peh + kh * 32, b0 + 32768 + du0 + kh * 1024);
    STAGE16(pel + kh * 32, b0 + 49152 + du0 + kh * 1024);
  }
  WAITVM(0);
  SBAR();

  int cur = 0;
#pragma unroll 1
  for (int t = 0; t < NT; ++t) {
    const unsigned char* rb = smem + cur * BUFB;
    unsigned char* wb = smem + (cur ^ 1) * BUFB;
    const size_t kb = (size_t)(t + 1) * 64;

    // ---- phase 1: read eh(8)+xh(4); stage ALL 8 units of t+1; 16 MFMA hh ----
    bf16x8 ehf[4][2], xhf[2][2];
#pragma unroll
    for (int c = 0; c < 4; ++c)
#pragma unroll
      for (int kh = 0; kh < 2; ++kh)
        ehf[c][kh] = *(const bf16x8*)(rb + erd + c * 2048 + kh * 1024);
#pragma unroll
    for (int r = 0; r < 2; ++r)
#pragma unroll
      for (int kh = 0; kh < 2; ++kh)
        xhf[r][kh] = *(const bf16x8*)(rb + xrd + r * 2048 + kh * 1024);
    if (t < NT - 1) {
#pragma unroll
      for (int kh = 0; kh < 2; ++kh) {
        STAGE16(pxh + kb + kh * 32, wb + du0 + kh * 1024);
        STAGE16(pxl + kb + kh * 32, wb + 16384 + du0 + kh * 1024);
        STAGE16(peh + kb + kh * 32, wb + 32768 + du0 + kh * 1024);
        STAGE16(pel + kb + kh * 32, wb + 49152 + du0 + kh * 1024);
      }
    }
    SBAR();
    LGKM0();
    __builtin_amdgcn_s_setprio(1);
#pragma unroll
    for (int kh = 0; kh < 2; ++kh)
#pragma unroll
      for (int c = 0; c < 4; ++c)
#pragma unroll
        for (int r = 0; r < 2; ++r)
          acc[c][r] = __builtin_amdgcn_mfma_f32_32x32x16_bf16(ehf[c][kh], xhf[r][kh], acc[c][r], 0, 0, 0);
    __builtin_amdgcn_s_setprio(0);
    SBAR();

    // ---- phase 2: read xl(4); 16 MFMA hl ----
    bf16x8 xlf[2][2];
#pragma unroll
    for (int r = 0; r < 2; ++r)
#pragma unroll
      for (int kh = 0; kh < 2; ++kh)
        xlf[r][kh] = *(const bf16x8*)(rb + 16384 + xrd + r * 2048 + kh * 1024);
    SBAR();
    LGKM0();
    __builtin_amdgcn_s_setprio(1);
#pragma unroll
    for (int kh = 0; kh < 2; ++kh)
#pragma unroll
      for (int c = 0; c < 4; ++c)
#pragma unroll
        for (int r = 0; r < 2; ++r)
          acc[c][r] = __builtin_amdgcn_mfma_f32_32x32x16_bf16(ehf[c][kh], xlf[r][kh], acc[c][r], 0, 0, 0);
    __builtin_amdgcn_s_setprio(0);
    SBAR();

    // ---- phase 3: read el(8); 16 MFMA lh; drain stages; swap ----
    bf16x8 elf[4][2];
#pragma unroll
    for (int c = 0; c < 4; ++c)
#pragma unroll
      for (int kh = 0; kh < 2; ++kh)
        elf[c][kh] = *(const bf16x8*)(rb + 49152 + erd - 32768 + c * 2048 + kh * 1024);
    SBAR();
    LGKM0();
    __builtin_amdgcn_s_setprio(1);
#pragma unroll
    for (int kh = 0; kh < 2; ++kh)
#pragma unroll
      for (int c = 0; c < 4; ++c)
#pragma unroll
        for (int r = 0; r < 2; ++r)
          acc[c][r] = __builtin_amdgcn_mfma_f32_32x32x16_bf16(elf[c][kh], xhf[r][kh], acc[c][r], 0, 0, 0);
    __builtin_amdgcn_s_setprio(0);
    WAITVM(0);       // stages issued in phase 1 (~2 phases ago): no stall
    SBAR();
    cur ^= 1;
  }

  // epilogue: per lane, xrow = bm*256 + rg*64 + r*32 + l31 holds 128 scores
  // (4 code-frags x 32). Ascending-code scan, strict > -> smallest code on tie.
#pragma unroll
  for (int r = 0; r < 2; ++r) {
    float bv = -3.4e38f;
    unsigned bcode = 0;
#pragma unroll
    for (int c = 0; c < 4; ++c)
#pragma unroll
      for (int q = 0; q < 4; ++q)
#pragma unroll
        for (int rr = 0; rr < 4; ++rr) {
          float v = acc[c][r][q * 4 + rr];
          unsigned cd = (unsigned)(cbase + c * 32 + q * 8 + rr);
          if (v > bv) { bv = v; bcode = cd; }
        }
    unsigned u = __float_as_uint(bv);
    u = (u & 0x80000000u) ? ~u : (u | 0x80000000u);        // order-preserving
    unsigned long long key =
        ((unsigned long long)u << 32) | (unsigned)(0xFFFFFFFFu ^ bcode);
    unsigned olo = __shfl_xor((unsigned)key, 32, 64);
    unsigned ohi = __shfl_xor((unsigned)(key >> 32), 32, 64);
    unsigned long long okey = ((unsigned long long)ohi << 32) | olo;
    if (okey > key) key = okey;
    if (lane < 32)
      atomicMax(&keys[bm * 256 + rg * 64 + r * 32 + l31], key);
  }
}

// ---------- gather q (exact f32), q_st out, per-row squared error ----------
__global__ void gather_k(const float* __restrict__ x, const float* __restrict__ embT,
                         const unsigned long long* __restrict__ keys,
                         float* __restrict__ qout, float* __restrict__ rowsum) {
  const int row = blockIdx.x;
  const int lane = threadIdx.x;
  const unsigned low = (unsigned)(keys[row] & 0xffffffffull);
  const int idx = (int)(~low);                 // stored 0xFFFFFFFF ^ code
  float4 q  = reinterpret_cast<const float4*>(embT + (size_t)idx * DDIM)[lane];
  float4 xv = reinterpret_cast<const float4*>(x + (size_t)row * DDIM)[lane];
  reinterpret_cast<float4*>(qout + (size_t)row * DDIM)[lane] = q;
  float dx = q.x - xv.x, dy = q.y - xv.y, dz = q.z - xv.z, dw = q.w - xv.w;
  float s = dx * dx + dy * dy + dz * dz + dw * dw;
#pragma unroll
  for (int mk = 32; mk; mk >>= 1) s += __shfl_xor(s, mk, 64);
  if (lane == 0) rowsum[row] = s;
}

// ---------- deterministic final loss reduce ----------
__global__ void loss_k(const float* __restrict__ rowsum, float* __restrict__ out) {
  __shared__ float sm[4];
  const int t = threadIdx.x;
  float s = 0.f;
  for (int j = t; j < N_ROWS; j += 256) s += rowsum[j];
#pragma unroll
  for (int mk = 32; mk; mk >>= 1) s += __shfl_xor(s, mk, 64);
  if ((t & 63) == 0) sm[t >> 6] = s;
  __syncthreads();
  if (t == 0) out[0] = 2.0f * (sm[0] + sm[1] + sm[2] + sm[3]) / (float)(N_ROWS * DDIM);
}

extern "C" void kernel_launch(void* const* d_in, const int* in_sizes, int n_in,
                              void* d_out, int out_size, void* d_ws, size_t ws_size,
                              hipStream_t stream) {
  const float* x   = (const float*)d_in[0];          // [16,1024,256] f32
  const float* emb = (const float*)d_in[1];          // [256,8192] f32
  float* qout = (float*)d_out;                       // 4,194,304 q_st + 1 loss

  char* w = (char*)d_ws;
  unsigned long long* keys = (unsigned long long*)w;                 // 128 KB
  float* rowsum = (float*)(w + 131072);                              // 64 KB
  __bf16* xhi = (__bf16*)(w + 196608);                               // 8 MB
  __bf16* xlo = xhi + (size_t)N_ROWS * DDIM;                         // 8 MB
  __bf16* ehi = xlo + (size_t)N_ROWS * DDIM;                         // 4 MB
  __bf16* elo = ehi + (size_t)N_CODES * DDIM;                        // 4 MB
  float*  embT = (float*)(elo + (size_t)N_CODES * DDIM);             // 8 MB
  float*  enorm = embT + (size_t)N_CODES * DDIM;                     // 32 KB

  hipFuncSetAttribute((const void*)vq_main_k,
                      hipFuncAttributeMaxDynamicSharedMemorySize, 2 * BUFB);

  hipMemsetAsync(keys, 0, N_ROWS * sizeof(unsigned long long), stream);  // atomicMax
  prep_x_k<<<4096, 256, 0, stream>>>(x, xhi, xlo);
  prep_e_k<<<dim3(N_CODES / 64, DDIM / 64), 256, 0, stream>>>(emb, ehi, elo, embT);
  enorm_k<<<N_CODES / 256, 256, 0, stream>>>(emb, enorm);
  vq_main_k<<<2048, 512, 2 * BUFB, stream>>>(xhi, xlo, ehi, elo, enorm, keys);
  gather_k<<<N_ROWS, 64, 0, stream>>>(x, embT, keys, qout, rowsum);
  loss_k<<<1, 256, 0, stream>>>(rowsum, qout + (size_t)N_ROWS * DDIM);
}

// Round 11
// 254.201 us; speedup vs baseline: 12.1732x; 1.0581x over previous
//
#include <hip/hip_runtime.h>
#include <hip/hip_bf16.h>
#include <cstdint>

// VQ quantizer: dist argmin over 8192 codes, gather, loss.
// R11: R7 math core (256x256 tile, 8 waves, BK=16, swapped 32x32x16, hi/lo
// 3-pass) with: 4x32KB LDS rotation, prefetch depth 3, counted WAITVM(8) +
// ONE barrier per step, NO intra-step barriers (writes target retired
// buffers only -> waves drift, compiler interleaves ds_read<->MFMA).

typedef __bf16 bf16x8 __attribute__((ext_vector_type(8)));
typedef __bf16 bf16x4 __attribute__((ext_vector_type(4)));
typedef float  f32x16 __attribute__((ext_vector_type(16)));

#define N_ROWS  16384
#define N_CODES 8192
#define DDIM    256
#define NT      16             // 256 / BK16
#define BUFB    32768          // xh 8K | xl 8K | eh 8K | el 8K

#define STAGE16(gptr, lptr) __builtin_amdgcn_global_load_lds( \
    (const __attribute__((address_space(1))) void*)(gptr),    \
    (__attribute__((address_space(3))) void*)(lptr), 16, 0, 0)

#define SBAR() do { asm volatile("" ::: "memory"); \
                    __builtin_amdgcn_s_barrier();  \
                    asm volatile("" ::: "memory"); } while (0)
#define WAITVM(N) asm volatile("s_waitcnt vmcnt(" #N ")" ::: "memory")

// ---------- prep: split x (f32) into bf16 hi/lo planes ----------
__global__ void prep_x_k(const float* __restrict__ x,
                         __bf16* __restrict__ xhi, __bf16* __restrict__ xlo) {
  int i = blockIdx.x * 256 + threadIdx.x;
  float4 v = reinterpret_cast<const float4*>(x)[i];
  float a[4] = {v.x, v.y, v.z, v.w};
  bf16x4 h, l;
#pragma unroll
  for (int j = 0; j < 4; ++j) {
    __bf16 hh = (__bf16)a[j];
    h[j] = hh;
    l[j] = (__bf16)(a[j] - (float)hh);
  }
  reinterpret_cast<bf16x4*>(xhi)[i] = h;
  reinterpret_cast<bf16x4*>(xlo)[i] = l;
}

// ---------- prep: transpose emb [256][8192] -> [8192][256]; split + f32 copy ----------
__global__ void prep_e_k(const float* __restrict__ emb,
                         __bf16* __restrict__ ehi, __bf16* __restrict__ elo,
                         float* __restrict__ embT) {
  __shared__ float tile[64][65];
  const int kb = blockIdx.x * 64, db = blockIdx.y * 64;
  const int t = threadIdx.x;
  const int tk = t & 63, td = t >> 6;
#pragma unroll
  for (int c = 0; c < 16; ++c) {
    int d = c * 4 + td;
    tile[d][tk] = emb[(size_t)(db + d) * N_CODES + kb + tk];
  }
  __syncthreads();
#pragma unroll
  for (int c = 0; c < 16; ++c) {
    int k = c * 4 + td;
    int d = tk;
    float v = tile[d][k];
    size_t o = (size_t)(kb + k) * DDIM + db + d;
    __bf16 h = (__bf16)v;
    embT[o] = v;
    ehi[o] = h;
    elo[o] = (__bf16)(v - (float)h);
  }
}

// ---------- prep: ||e_k||^2 in exact f32 ----------
__global__ void enorm_k(const float* __restrict__ emb, float* __restrict__ enorm) {
  int k = blockIdx.x * 256 + threadIdx.x;
  float s = 0.f;
  for (int d = 0; d < DDIM; ++d) {
    float v = emb[(size_t)d * N_CODES + k];
    s += v * v;
  }
  enorm[k] = s;
}

// ---------- main: 256x256 tile, 8 waves, BK=16, 4-buf depth-3 pipeline ----
// LDS buffer (32KB), 1KB units (64 lanes x 16B, one frag each):
//   [0,8): xh row-unit | [8,16): xl | [16,24): eh code-unit | [24,32): el
// Wave w stages units {xh[w], xl[w], eh[w], el[w]} of step t+3 per step.
// Correctness: writes target buffer (t+3)&3 == retired buffer (last read at
// step t-1, reads complete before step t-1's end barrier). Step-end
// WAITVM(8) retires step t+1's 4 loads (issued at t-2); SBAR publishes.
// A-operand = e-frag (code=lane&31, k-chunk=lane>>5), B-operand = x-frag.
// C layout (m74): col(lane&31)=xrow, code=(reg&3)+8*(reg>>2)+4*(lane>>5).
__global__ __launch_bounds__(512, 2) void vq_main_k(
    const __bf16* __restrict__ xhi, const __bf16* __restrict__ xlo,
    const __bf16* __restrict__ ehi, const __bf16* __restrict__ elo,
    const float* __restrict__ enorm, unsigned long long* __restrict__ keys) {
  extern __shared__ __align__(16) unsigned char smem[];   // 4 * 32KB

  const int tid = threadIdx.x;
  const int wid = tid >> 6, lane = tid & 63;
  const int cg = wid >> 2, rg = wid & 3;      // code-half(128), row-quarter(64)
  const int l31 = lane & 31, lh = lane >> 5;

  // XCD swizzle: each XCD owns an 8-bm window (2048 rows, L2-resident)
  // swept over all 32 bn panels. 2048 % 8 == 0 -> bijective.
  const int orig = blockIdx.x;
  const int j = orig >> 3;
  const int bm = (orig & 7) * 8 + (j & 7);    // 0..63
  const int bn = j >> 3;                      // 0..31

  // acc init = -||e||^2/2  (argmin dist == argmax(dot - en/2))
  const int cbase = bn * 256 + cg * 128 + lh * 4;
  f32x16 acc[4][2];
#pragma unroll
  for (int c = 0; c < 4; ++c) {
    f32x16 ci;
#pragma unroll
    for (int q = 0; q < 4; ++q)
#pragma unroll
      for (int r = 0; r < 4; ++r)
        ci[q * 4 + r] = -0.5f * enorm[cbase + c * 32 + q * 8 + r];
    acc[c][0] = ci; acc[c][1] = ci;
  }
  __builtin_amdgcn_sched_barrier(0);   // enorm vmem retires before staging

  // staging sources (wave-owned row/code unit = wid)
  const size_t aoff = (size_t)(bm * 256 + wid * 32 + l31) * 512 + (size_t)lh * 16;
  const size_t boff = (size_t)(bn * 256 + wid * 32 + l31) * 512 + (size_t)lh * 16;
  const char* pxh = (const char*)xhi + aoff;
  const char* pxl = (const char*)xlo + aoff;
  const char* peh = (const char*)ehi + boff;
  const char* pel = (const char*)elo + boff;
  const int dxh = wid * 1024, dxl = 8192 + wid * 1024;
  const int deh = 16384 + wid * 1024, del = 24576 + wid * 1024;

  // fragment read offsets (lane-linear)
  const int xrd = rg * 2048 + lane * 16;           // + r*1024 ; xl at +8192
  const int erd = 16384 + cg * 4096 + lane * 16;   // + c*1024 ; el at +8192

  // prologue: stage steps 0,1,2 -> buffers 0,1,2 (4 loads each per wave)
#pragma unroll
  for (int s = 0; s < 3; ++s) {
    unsigned char* bs = smem + s * BUFB;
    STAGE16(pxh + s * 32, bs + dxh);
    STAGE16(pxl + s * 32, bs + dxl);
    STAGE16(peh + s * 32, bs + deh);
    STAGE16(pel + s * 32, bs + del);
  }
  WAITVM(8);         // step 0's 4 landed; steps 1,2 in flight
  SBAR();

#pragma unroll 1
  for (int t = 0; t < NT; ++t) {
    int s = t + 3; if (s >= NT) s -= NT;     // wrap: writes land in dead buffers
    const unsigned char* rb = smem + (t & 3) * BUFB;
    unsigned char* wb = smem + (s & 3) * BUFB;
    const size_t kb = (size_t)s * 32;

    // stage first (HBM latency hides under this step's compute)
    STAGE16(pxh + kb, wb + dxh);
    STAGE16(pxl + kb, wb + dxl);
    STAGE16(peh + kb, wb + deh);
    STAGE16(pel + kb, wb + del);

    // reads + 24 MFMA: compiler interleaves with fine-grained lgkmcnt;
    // waves drift (no intra-step barrier) -> cross-wave pipe overlap.
    bf16x8 ehf[4], xhf[2], xlf[2], elf[4];
#pragma unroll
    for (int c = 0; c < 4; ++c) ehf[c] = *(const bf16x8*)(rb + erd + c * 1024);
#pragma unroll
    for (int r = 0; r < 2; ++r) xhf[r] = *(const bf16x8*)(rb + xrd + r * 1024);
#pragma unroll
    for (int r = 0; r < 2; ++r) xlf[r] = *(const bf16x8*)(rb + 8192 + xrd + r * 1024);
#pragma unroll
    for (int c = 0; c < 4; ++c) elf[c] = *(const bf16x8*)(rb + 8192 + erd + c * 1024);

#pragma unroll
    for (int c = 0; c < 4; ++c)
#pragma unroll
      for (int r = 0; r < 2; ++r)
        acc[c][r] = __builtin_amdgcn_mfma_f32_32x32x16_bf16(ehf[c], xhf[r], acc[c][r], 0, 0, 0);
#pragma unroll
    for (int c = 0; c < 4; ++c)
#pragma unroll
      for (int r = 0; r < 2; ++r)
        acc[c][r] = __builtin_amdgcn_mfma_f32_32x32x16_bf16(ehf[c], xlf[r], acc[c][r], 0, 0, 0);
#pragma unroll
    for (int c = 0; c < 4; ++c)
#pragma unroll
      for (int r = 0; r < 2; ++r)
        acc[c][r] = __builtin_amdgcn_mfma_f32_32x32x16_bf16(elf[c], xhf[r], acc[c][r], 0, 0, 0);

    WAITVM(8);       // t+1's 4 loads (issued at t-2) retired; t+2,t+3 in flight
    SBAR();
  }
  WAITVM(0);         // drain wrapped tail stages before LDS teardown

  // epilogue: per lane, xrow = bm*256 + rg*64 + r*32 + l31 holds 128 scores
  // (4 code-frags x 32). Ascending-code scan, strict > -> smallest code on tie.
#pragma unroll
  for (int r = 0; r < 2; ++r) {
    float bv = -3.4e38f;
    unsigned bcode = 0;
#pragma unroll
    for (int c = 0; c < 4; ++c)
#pragma unroll
      for (int q = 0; q < 4; ++q)
#pragma unroll
        for (int rr = 0; rr < 4; ++rr) {
          float v = acc[c][r][q * 4 + rr];
          unsigned cd = (unsigned)(cbase + c * 32 + q * 8 + rr);
          if (v > bv) { bv = v; bcode = cd; }
        }
    unsigned u = __float_as_uint(bv);
    u = (u & 0x80000000u) ? ~u : (u | 0x80000000u);        // order-preserving
    unsigned long long key =
        ((unsigned long long)u << 32) | (unsigned)(0xFFFFFFFFu ^ bcode);
    unsigned olo = __shfl_xor((unsigned)key, 32, 64);
    unsigned ohi = __shfl_xor((unsigned)(key >> 32), 32, 64);
    unsigned long long okey = ((unsigned long long)ohi << 32) | olo;
    if (okey > key) key = okey;
    if (lane < 32)
      atomicMax(&keys[bm * 256 + rg * 64 + r * 32 + l31], key);
  }
}

// ---------- gather q (exact f32), q_st out, per-row squared error ----------
__global__ void gather_k(const float* __restrict__ x, const float* __restrict__ embT,
                         const unsigned long long* __restrict__ keys,
                         float* __restrict__ qout, float* __restrict__ rowsum) {
  const int row = blockIdx.x;
  const int lane = threadIdx.x;
  const unsigned low = (unsigned)(keys[row] & 0xffffffffull);
  const int idx = (int)(~low);                 // stored 0xFFFFFFFF ^ code
  float4 q  = reinterpret_cast<const float4*>(embT + (size_t)idx * DDIM)[lane];
  float4 xv = reinterpret_cast<const float4*>(x + (size_t)row * DDIM)[lane];
  reinterpret_cast<float4*>(qout + (size_t)row * DDIM)[lane] = q;
  float dx = q.x - xv.x, dy = q.y - xv.y, dz = q.z - xv.z, dw = q.w - xv.w;
  float s = dx * dx + dy * dy + dz * dz + dw * dw;
#pragma unroll
  for (int mk = 32; mk; mk >>= 1) s += __shfl_xor(s, mk, 64);
  if (lane == 0) rowsum[row] = s;
}

// ---------- deterministic final loss reduce ----------
__global__ void loss_k(const float* __restrict__ rowsum, float* __restrict__ out) {
  __shared__ float sm[4];
  const int t = threadIdx.x;
  float s = 0.f;
  for (int j = t; j < N_ROWS; j += 256) s += rowsum[j];
#pragma unroll
  for (int mk = 32; mk; mk >>= 1) s += __shfl_xor(s, mk, 64);
  if ((t & 63) == 0) sm[t >> 6] = s;
  __syncthreads();
  if (t == 0) out[0] = 2.0f * (sm[0] + sm[1] + sm[2] + sm[3]) / (float)(N_ROWS * DDIM);
}

extern "C" void kernel_launch(void* const* d_in, const int* in_sizes, int n_in,
                              void* d_out, int out_size, void* d_ws, size_t ws_size,
                              hipStream_t stream) {
  const float* x   = (const float*)d_in[0];          // [16,1024,256] f32
  const float* emb = (const float*)d_in[1];          // [256,8192] f32
  float* qout = (float*)d_out;                       // 4,194,304 q_st + 1 loss

  char* w = (char*)d_ws;
  unsigned long long* keys = (unsigned long long*)w;                 // 128 KB
  float* rowsum = (float*)(w + 131072);                              // 64 KB
  __bf16* xhi = (__bf16*)(w + 196608);                               // 8 MB
  __bf16* xlo = xhi + (size_t)N_ROWS * DDIM;                         // 8 MB
  __bf16* ehi = xlo + (size_t)N_ROWS * DDIM;                         // 4 MB
  __bf16* elo = ehi + (size_t)N_CODES * DDIM;                        // 4 MB
  float*  embT = (float*)(elo + (size_t)N_CODES * DDIM);             // 8 MB
  float*  enorm = embT + (size_t)N_CODES * DDIM;                     // 32 KB

  hipFuncSetAttribute((const void*)vq_main_k,
                      hipFuncAttributeMaxDynamicSharedMemorySize, 4 * BUFB);

  hipMemsetAsync(keys, 0, N_ROWS * sizeof(unsigned long long), stream);  // atomicMax
  prep_x_k<<<4096, 256, 0, stream>>>(x, xhi, xlo);
  prep_e_k<<<dim3(N_CODES / 64, DDIM / 64), 256, 0, stream>>>(emb, ehi, elo, embT);
  enorm_k<<<N_CODES / 256, 256, 0, stream>>>(emb, enorm);
  vq_main_k<<<2048, 512, 4 * BUFB, stream>>>(xhi, xlo, ehi, elo, enorm, keys);
  gather_k<<<N_ROWS, 64, 0, stream>>>(x, embT, keys, qout, rowsum);
  loss_k<<<1, 256, 0, stream>>>(rowsum, qout + (size_t)N_ROWS * DDIM);
}